// Round 3
// baseline (352.478 us; speedup 1.0000x reference)
//
#include <hip/hip_runtime.h>
#include <math.h>

#define TOK_PER_BLK 4
#define THREADS 256
#define NROWS 24
#define PCOL 68        // 64 partials + 4 pad
#define TAU_INV 20.0f  // 1/0.05

// ---------------------------------------------------------------------------
// Prelude: fold (1+gamma) into the 24 weight rows once, into workspace.
// dot(w, x*(1+g)) == dot(w*(1+g), x), and the rms 'scale' uses raw ||x||, so
// the main kernel never touches gamma: saves 16 VGPRs + 384 mults/thread and
// collapses the 3 weight base pointers into one.
// ---------------------------------------------------------------------------
__global__ void fold_gamma(const float* __restrict__ w_res,
                           const float* __restrict__ w_pre,
                           const float* __restrict__ w_post,
                           const float* __restrict__ gamma,
                           float* __restrict__ wf) {
    const int idx = blockIdx.x * THREADS + threadIdx.x;   // 0..98303
    const int e = idx >> 12, k = idx & 4095;              // e uniform per block
    const float* src = (e < 16) ? (w_res + ((size_t)e << 12))
                     : (e < 20) ? (w_pre + ((size_t)(e - 16) << 12))
                                : (w_post + ((size_t)(e - 20) << 12));
    wf[idx] = src[k] * (1.0f + gamma[k]);
}

// One block = 4 tokens, 256 threads. Thread tid holds float4 (q*256+tid) of
// each token in REGISTERS. Phase 2 streams pre-folded weight rows through a
// CHUNK=1 register double-buffer (no LDS staging, no barriers inside the loop
// — R5's 48-barrier LDS pipeline DROPPED VALUBusy 35->31 and HBM 2244->1733).
// Register budget: p 64 + wA 16 + wB 16 + temps ~15 = ~110 < 128-cap from
// __launch_bounds__(256,4). Tripwire for the known allocator failure mode:
// WRITE_SIZE > 140 MB means p spilled to scratch again (R4: +70MB, R5: +48MB).
// NOTE (R6): no token-pasting macros for the buffers — P##0.x lexes 0.x as a
// pp-number and the paste fails. Named arrays + by-ref lambdas (R4 pattern).
__global__ __launch_bounds__(THREADS, 4)
void hc_fused(const float* __restrict__ resid,
              const float* __restrict__ wf,
              const float* __restrict__ beta_res,
              const float* __restrict__ beta_pre,
              const float* __restrict__ beta_post,
              const float* __restrict__ p_alpha_res,
              const float* __restrict__ p_alpha_pre,
              const float* __restrict__ p_alpha_post,
              float* __restrict__ out)
{
    __shared__ __align__(16) float sh_part[NROWS * TOK_PER_BLK][PCOL]; // 26.1 KB
    __shared__ __align__(16) float sh_ssqp[TOK_PER_BLK][PCOL];
    __shared__ float sh_raw[TOK_PER_BLK][NROWS];
    __shared__ float sh_ssq[TOK_PER_BLK];
    __shared__ float sh_H[TOK_PER_BLK][NROWS];  // [0..15]=H_res, [16..19]=H_pre, [20..23]=H_post

    const int tid  = threadIdx.x;
    const int wave = tid >> 6;
    const int lane = tid & 63;
    const long tok0 = (long)blockIdx.x * TOK_PER_BLK;

    // ---------------- Phase 1: global -> registers + sumsq ----------------
    const float4* hp = (const float4*)resid + tok0 * 1024;
    float4 p[TOK_PER_BLK][4];
    #pragma unroll
    for (int m = 0; m < TOK_PER_BLK; ++m) {
        #pragma unroll
        for (int q = 0; q < 4; ++q)
            p[m][q] = hp[m * 1024 + q * 256 + tid];
    }
    #pragma unroll
    for (int m = 0; m < TOK_PER_BLK; ++m) {
        float s = 0.f;
        #pragma unroll
        for (int q = 0; q < 4; ++q) {
            float4 v = p[m][q];
            s += v.x * v.x + v.y * v.y + v.z * v.z + v.w * v.w;
        }
        s += __shfl_xor(s, 16, 64);
        s += __shfl_xor(s, 32, 64);
        if (lane < 16) sh_ssqp[m][wave * 16 + lane] = s;
    }

    // ---------------- Phase 2: 24 dots, CHUNK=1 register dbuf ----------------
    const float4* wp = (const float4*)wf;    // [24][1024] float4, pre-folded

    auto load_row = [&](int e, float4 (&w)[4]) {
        const float4* wr = wp + ((size_t)e << 10);
        #pragma unroll
        for (int q = 0; q < 4; ++q) w[q] = wr[q * 256 + tid];
    };
    auto comp_row = [&](int e, const float4 (&w)[4]) {
        #pragma unroll
        for (int m = 0; m < TOK_PER_BLK; ++m) {
            float a = w[0].x * p[m][0].x + w[0].y * p[m][0].y + w[0].z * p[m][0].z + w[0].w * p[m][0].w
                    + w[1].x * p[m][1].x + w[1].y * p[m][1].y + w[1].z * p[m][1].z + w[1].w * p[m][1].w
                    + w[2].x * p[m][2].x + w[2].y * p[m][2].y + w[2].z * p[m][2].z + w[2].w * p[m][2].w
                    + w[3].x * p[m][3].x + w[3].y * p[m][3].y + w[3].z * p[m][3].z + w[3].w * p[m][3].w;
            a += __shfl_xor(a, 16, 64);
            a += __shfl_xor(a, 32, 64);
            if (lane < 16) sh_part[e * TOK_PER_BLK + m][wave * 16 + lane] = a;
        }
    };

    float4 wA[4], wB[4];
    load_row(0, wA);
    #pragma unroll 1
    for (int cc = 0; cc < 12; ++cc) {
        load_row(2 * cc + 1, wB);
        comp_row(2 * cc, wA);
        if (cc < 11) load_row(2 * cc + 2, wA);
        comp_row(2 * cc + 1, wB);
    }
    __syncthreads();

    // ---------------- Reduce: parallel column sums ----------------
    if (tid < NROWS * TOK_PER_BLK) {           // 96 threads: one (row,token) each
        const int e = tid >> 2, m = tid & 3;
        const float4* src = (const float4*)&sh_part[e * TOK_PER_BLK + m][0];
        float4 s4 = src[0];
        #pragma unroll
        for (int j = 1; j < 16; ++j) {
            float4 v = src[j];
            s4.x += v.x; s4.y += v.y; s4.z += v.z; s4.w += v.w;
        }
        sh_raw[m][e] = s4.x + s4.y + s4.z + s4.w;
    } else if (tid < NROWS * TOK_PER_BLK + TOK_PER_BLK) {
        const int m = tid - NROWS * TOK_PER_BLK;
        const float4* src = (const float4*)&sh_ssqp[m][0];
        float4 s4 = src[0];
        #pragma unroll
        for (int j = 1; j < 16; ++j) {
            float4 v = src[j];
            s4.x += v.x; s4.y += v.y; s4.z += v.z; s4.w += v.w;
        }
        sh_ssq[m] = s4.x + s4.y + s4.z + s4.w;
    }
    __syncthreads();

    // ---------------- Phase 3: sinkhorn + gates (one wave per token) --------
    {
        const int m   = wave;
        const int idx = lane & 15;     // (i,j): i = idx>>2, j = idx&3
        const int jj  = idx & 3;

        float ss    = sh_ssq[m];
        float scale = 64.0f / fmaxf(sqrtf(ss), 1e-12f);

        const float a_res  = p_alpha_res[0];
        const float a_pre  = p_alpha_pre[0];
        const float a_post = p_alpha_post[0];

        float Z = (beta_res[idx] + a_res * scale * sh_raw[m][idx]) * TAU_INV;
        float u = 0.f, v = 0.f;
        #pragma unroll 1
        for (int it = 0; it < 10; ++it) {
            float t  = Z + v;
            float mx = t;
            mx = fmaxf(mx, __shfl_xor(mx, 1, 64));
            mx = fmaxf(mx, __shfl_xor(mx, 2, 64));
            float sm = __expf(t - mx);
            sm += __shfl_xor(sm, 1, 64);
            sm += __shfl_xor(sm, 2, 64);
            u = -(mx + __logf(sm));
            t  = Z + u;
            mx = t;
            mx = fmaxf(mx, __shfl_xor(mx, 4, 64));
            mx = fmaxf(mx, __shfl_xor(mx, 8, 64));
            sm = __expf(t - mx);
            sm += __shfl_xor(sm, 4, 64);
            sm += __shfl_xor(sm, 8, 64);
            v = -(mx + __logf(sm));
        }
        float P = __expf(Z + u + v);
        if (lane < 16) sh_H[m][idx] = P;

        float lpre = beta_pre[jj] + a_pre * scale * sh_raw[m][16 + jj];
        float mxp = lpre;
        mxp = fmaxf(mxp, __shfl_xor(mxp, 1, 64));
        mxp = fmaxf(mxp, __shfl_xor(mxp, 2, 64));
        float ep = __expf(lpre - mxp);
        float sp = ep;
        sp += __shfl_xor(sp, 1, 64);
        sp += __shfl_xor(sp, 2, 64);
        float hpre = ep / sp;
        float lpost = beta_post[jj] + a_post * scale * sh_raw[m][20 + jj];
        float hpost = 2.0f / (1.0f + __expf(-lpost));
        if (lane < 4) { sh_H[m][16 + jj] = hpre; sh_H[m][20 + jj] = hpost; }
    }
    __syncthreads();

    // ---------------- Phase 4: remix + branch, store (FULLY UNROLLED) -------
    #pragma unroll
    for (int m = 0; m < TOK_PER_BLK; ++m) {
        float Hr[16], Hp[4], Ho[4];
        #pragma unroll
        for (int k = 0; k < 16; ++k) Hr[k] = sh_H[m][k];
        #pragma unroll
        for (int s = 0; s < 4; ++s) { Hp[s] = sh_H[m][16 + s]; Ho[s] = sh_H[m][20 + s]; }

        float4 br;
        br.x = Hp[0]*p[m][0].x + Hp[1]*p[m][1].x + Hp[2]*p[m][2].x + Hp[3]*p[m][3].x;
        br.y = Hp[0]*p[m][0].y + Hp[1]*p[m][1].y + Hp[2]*p[m][2].y + Hp[3]*p[m][3].y;
        br.z = Hp[0]*p[m][0].z + Hp[1]*p[m][1].z + Hp[2]*p[m][2].z + Hp[3]*p[m][3].z;
        br.w = Hp[0]*p[m][0].w + Hp[1]*p[m][1].w + Hp[2]*p[m][2].w + Hp[3]*p[m][3].w;

        float4* op = (float4*)out + (tok0 + m) * 1024;
        #pragma unroll
        for (int i = 0; i < 4; ++i) {
            float4 o;
            o.x = Hr[i*4+0]*p[m][0].x + Hr[i*4+1]*p[m][1].x + Hr[i*4+2]*p[m][2].x + Hr[i*4+3]*p[m][3].x + Ho[i]*br.x;
            o.y = Hr[i*4+0]*p[m][0].y + Hr[i*4+1]*p[m][1].y + Hr[i*4+2]*p[m][2].y + Hr[i*4+3]*p[m][3].y + Ho[i]*br.y;
            o.z = Hr[i*4+0]*p[m][0].z + Hr[i*4+1]*p[m][1].z + Hr[i*4+2]*p[m][2].z + Hr[i*4+3]*p[m][3].z + Ho[i]*br.z;
            o.w = Hr[i*4+0]*p[m][0].w + Hr[i*4+1]*p[m][1].w + Hr[i*4+2]*p[m][2].w + Hr[i*4+3]*p[m][3].w + Ho[i]*br.w;
            op[i * 256 + tid] = o;
        }
    }
}

extern "C" void kernel_launch(void* const* d_in, const int* in_sizes, int n_in,
                              void* d_out, int out_size, void* d_ws, size_t ws_size,
                              hipStream_t stream) {
    const float* resid      = (const float*)d_in[0];
    const float* gamma      = (const float*)d_in[1];
    const float* w_res      = (const float*)d_in[2];
    const float* w_pre      = (const float*)d_in[3];
    const float* w_post     = (const float*)d_in[4];
    const float* beta_res   = (const float*)d_in[5];
    const float* beta_pre   = (const float*)d_in[6];
    const float* beta_post  = (const float*)d_in[7];
    const float* alpha_res  = (const float*)d_in[8];
    const float* alpha_pre  = (const float*)d_in[9];
    const float* alpha_post = (const float*)d_in[10];
    float* out = (float*)d_out;

    float* wf = (float*)d_ws;                     // needs 24*4096*4 = 384 KB
    (void)ws_size;

    fold_gamma<<<NROWS * 4096 / THREADS, THREADS, 0, stream>>>(
        w_res, w_pre, w_post, gamma, wf);

    const int ntok = in_sizes[0] / 4096;          // B*T = 8192
    const int grid = ntok / TOK_PER_BLK;          // 2048

    hc_fused<<<grid, THREADS, 0, stream>>>(resid, wf, beta_res, beta_pre,
                                           beta_post, alpha_res, alpha_pre,
                                           alpha_post, out);
}

// Round 4
// 297.790 us; speedup vs baseline: 1.1836x; 1.1836x over previous
//
#include <hip/hip_runtime.h>
#include <math.h>

#define TOK_PER_BLK 4
#define THREADS 256
#define NROWS 24
#define PCOL 68        // 64 partials + 4 pad
#define TAU_INV 20.0f  // 1/0.05

// ---------------------------------------------------------------------------
// Prelude: fold (1+gamma) into the 24 weight rows once, into workspace.
// dot(w, x*(1+g)) == dot(w*(1+g), x); rms 'scale' uses raw ||x||, so the main
// kernel never touches gamma.
// ---------------------------------------------------------------------------
__global__ void fold_gamma(const float* __restrict__ w_res,
                           const float* __restrict__ w_pre,
                           const float* __restrict__ w_post,
                           const float* __restrict__ gamma,
                           float* __restrict__ wf) {
    const int idx = blockIdx.x * THREADS + threadIdx.x;   // 0..98303
    const int e = idx >> 12, k = idx & 4095;              // e uniform per block
    const float* src = (e < 16) ? (w_res + ((size_t)e << 12))
                     : (e < 20) ? (w_pre + ((size_t)(e - 16) << 12))
                                : (w_post + ((size_t)(e - 20) << 12));
    wf[idx] = src[k] * (1.0f + gamma[k]);
}

// One block = 4 tokens, 256 threads; thread tid holds float4 (q*256+tid) of
// each token in REGISTERS; weights stream through a CHUNK=1 register dbuf.
//
// ALLOCATOR NOTE (R4/R5/R7 evidence): this kernel gets perf-hint-tagged
// memory-bound and the allocator targets 2x the declared min-waves/EU, then
// spills to that target:
//   launch_bounds(256,3) -> 84 VGPRs (=512/6), +70MB scratch
//   launch_bounds(256,4) -> 64 VGPRs (=512/8), +62MB scratch
// So declare (256,2): predicted target 4 waves/SIMD -> 128-reg budget, which
// the true live set (p 64 + wA 16 + wB 16 + temps ~15) fits with ZERO spill.
// Tripwire: VGPR_Count still <=84 or WRITE_SIZE >140MB means the 2x-target
// theory is wrong -> next step is LDS-staged x (45-reg design), not more
// launch_bounds fiddling.
__global__ __launch_bounds__(THREADS, 2)
void hc_fused(const float* __restrict__ resid,
              const float* __restrict__ wf,
              const float* __restrict__ beta_res,
              const float* __restrict__ beta_pre,
              const float* __restrict__ beta_post,
              const float* __restrict__ p_alpha_res,
              const float* __restrict__ p_alpha_pre,
              const float* __restrict__ p_alpha_post,
              float* __restrict__ out)
{
    __shared__ __align__(16) float sh_part[NROWS * TOK_PER_BLK][PCOL]; // 26.1 KB
    __shared__ __align__(16) float sh_ssqp[TOK_PER_BLK][PCOL];
    __shared__ float sh_raw[TOK_PER_BLK][NROWS];
    __shared__ float sh_ssq[TOK_PER_BLK];
    __shared__ float sh_M[TOK_PER_BLK][16];  // combined remix matrix per token

    const int tid  = threadIdx.x;
    const int wave = tid >> 6;
    const int lane = tid & 63;
    const long tok0 = (long)blockIdx.x * TOK_PER_BLK;

    // ---------------- Phase 1: global -> registers + sumsq ----------------
    const float4* hp = (const float4*)resid + tok0 * 1024;
    float4 p[TOK_PER_BLK][4];
    #pragma unroll
    for (int m = 0; m < TOK_PER_BLK; ++m) {
        #pragma unroll
        for (int q = 0; q < 4; ++q)
            p[m][q] = hp[m * 1024 + q * 256 + tid];
    }
    #pragma unroll
    for (int m = 0; m < TOK_PER_BLK; ++m) {
        float s = 0.f;
        #pragma unroll
        for (int q = 0; q < 4; ++q) {
            float4 v = p[m][q];
            s += v.x * v.x + v.y * v.y + v.z * v.z + v.w * v.w;
        }
        s += __shfl_xor(s, 16, 64);
        s += __shfl_xor(s, 32, 64);
        if (lane < 16) sh_ssqp[m][wave * 16 + lane] = s;
    }

    // ---------------- Phase 2: 24 dots, CHUNK=1 register dbuf ----------------
    const float4* wp = (const float4*)wf;    // [24][1024] float4, pre-folded

    auto load_row = [&](int e, float4 (&w)[4]) {
        const float4* wr = wp + ((size_t)e << 10);
        #pragma unroll
        for (int q = 0; q < 4; ++q) w[q] = wr[q * 256 + tid];
    };
    auto comp_row = [&](int e, const float4 (&w)[4]) {
        #pragma unroll
        for (int m = 0; m < TOK_PER_BLK; ++m) {
            float a = w[0].x * p[m][0].x + w[0].y * p[m][0].y + w[0].z * p[m][0].z + w[0].w * p[m][0].w
                    + w[1].x * p[m][1].x + w[1].y * p[m][1].y + w[1].z * p[m][1].z + w[1].w * p[m][1].w
                    + w[2].x * p[m][2].x + w[2].y * p[m][2].y + w[2].z * p[m][2].z + w[2].w * p[m][2].w
                    + w[3].x * p[m][3].x + w[3].y * p[m][3].y + w[3].z * p[m][3].z + w[3].w * p[m][3].w;
            a += __shfl_xor(a, 16, 64);
            a += __shfl_xor(a, 32, 64);
            if (lane < 16) sh_part[e * TOK_PER_BLK + m][wave * 16 + lane] = a;
        }
    };

    float4 wA[4], wB[4];
    load_row(0, wA);
    #pragma unroll 1
    for (int cc = 0; cc < 12; ++cc) {
        load_row(2 * cc + 1, wB);
        comp_row(2 * cc, wA);
        if (cc < 11) load_row(2 * cc + 2, wA);
        comp_row(2 * cc + 1, wB);
    }
    __syncthreads();

    // ---------------- Reduce: parallel column sums ----------------
    if (tid < NROWS * TOK_PER_BLK) {           // 96 threads: one (row,token) each
        const int e = tid >> 2, m = tid & 3;
        const float4* src = (const float4*)&sh_part[e * TOK_PER_BLK + m][0];
        float4 s4 = src[0];
        #pragma unroll
        for (int j = 1; j < 16; ++j) {
            float4 v = src[j];
            s4.x += v.x; s4.y += v.y; s4.z += v.z; s4.w += v.w;
        }
        sh_raw[m][e] = s4.x + s4.y + s4.z + s4.w;
    } else if (tid < NROWS * TOK_PER_BLK + TOK_PER_BLK) {
        const int m = tid - NROWS * TOK_PER_BLK;
        const float4* src = (const float4*)&sh_ssqp[m][0];
        float4 s4 = src[0];
        #pragma unroll
        for (int j = 1; j < 16; ++j) {
            float4 v = src[j];
            s4.x += v.x; s4.y += v.y; s4.z += v.z; s4.w += v.w;
        }
        sh_ssq[m] = s4.x + s4.y + s4.z + s4.w;
    }
    __syncthreads();

    // ---------------- Phase 3: sinkhorn + gates (one wave per token) --------
    // Produces the COMBINED matrix M[i][j] = Hres[i][j] + Hpost[i]*Hpre[j],
    // so phase 4 is just out = M . x per d-element (64 FMA/token, no branch).
    {
        const int m   = wave;
        const int idx = lane & 15;     // (i,j): i = idx>>2, j = idx&3
        const int jj  = idx & 3;

        float ss    = sh_ssq[m];
        float scale = 64.0f / fmaxf(sqrtf(ss), 1e-12f);

        const float a_res  = p_alpha_res[0];
        const float a_pre  = p_alpha_pre[0];
        const float a_post = p_alpha_post[0];

        float Z = (beta_res[idx] + a_res * scale * sh_raw[m][idx]) * TAU_INV;
        float u = 0.f, v = 0.f;
        #pragma unroll 1
        for (int it = 0; it < 10; ++it) {
            float t  = Z + v;
            float mx = t;
            mx = fmaxf(mx, __shfl_xor(mx, 1, 64));
            mx = fmaxf(mx, __shfl_xor(mx, 2, 64));
            float sm = __expf(t - mx);
            sm += __shfl_xor(sm, 1, 64);
            sm += __shfl_xor(sm, 2, 64);
            u = -(mx + __logf(sm));
            t  = Z + u;
            mx = t;
            mx = fmaxf(mx, __shfl_xor(mx, 4, 64));
            mx = fmaxf(mx, __shfl_xor(mx, 8, 64));
            sm = __expf(t - mx);
            sm += __shfl_xor(sm, 4, 64);
            sm += __shfl_xor(sm, 8, 64);
            v = -(mx + __logf(sm));
        }
        float P = __expf(Z + u + v);           // Hres[i][j] at lane idx

        float lpre = beta_pre[jj] + a_pre * scale * sh_raw[m][16 + jj];
        float mxp = lpre;
        mxp = fmaxf(mxp, __shfl_xor(mxp, 1, 64));
        mxp = fmaxf(mxp, __shfl_xor(mxp, 2, 64));
        float ep = __expf(lpre - mxp);
        float sp = ep;
        sp += __shfl_xor(sp, 1, 64);
        sp += __shfl_xor(sp, 2, 64);
        float hpre = ep / sp;                  // Hpre[jj] (jj == this lane's j)
        float lpost = beta_post[jj] + a_post * scale * sh_raw[m][20 + jj];
        float hpost = 2.0f / (1.0f + __expf(-lpost));  // Hpost[jj]

        // Hpost[i]: lane (idx>>2) in 0..3 computed hpost for jj == i.
        float hpost_i = __shfl(hpost, idx >> 2, 64);
        float Mv = P + hpost_i * hpre;
        if (lane < 16) sh_M[m][idx] = Mv;
    }
    __syncthreads();

    // ---------------- Phase 4: out = M . x, store (FULLY UNROLLED) ----------
    #pragma unroll
    for (int m = 0; m < TOK_PER_BLK; ++m) {
        float Mv[16];
        #pragma unroll
        for (int k = 0; k < 16; ++k) Mv[k] = sh_M[m][k];   // broadcast reads

        float4* op = (float4*)out + (tok0 + m) * 1024;
        #pragma unroll
        for (int i = 0; i < 4; ++i) {
            float4 o;
            o.x = Mv[i*4+0]*p[m][0].x + Mv[i*4+1]*p[m][1].x + Mv[i*4+2]*p[m][2].x + Mv[i*4+3]*p[m][3].x;
            o.y = Mv[i*4+0]*p[m][0].y + Mv[i*4+1]*p[m][1].y + Mv[i*4+2]*p[m][2].y + Mv[i*4+3]*p[m][3].y;
            o.z = Mv[i*4+0]*p[m][0].z + Mv[i*4+1]*p[m][1].z + Mv[i*4+2]*p[m][2].z + Mv[i*4+3]*p[m][3].z;
            o.w = Mv[i*4+0]*p[m][0].w + Mv[i*4+1]*p[m][1].w + Mv[i*4+2]*p[m][2].w + Mv[i*4+3]*p[m][3].w;
            op[i * 256 + tid] = o;
        }
    }
}

extern "C" void kernel_launch(void* const* d_in, const int* in_sizes, int n_in,
                              void* d_out, int out_size, void* d_ws, size_t ws_size,
                              hipStream_t stream) {
    const float* resid      = (const float*)d_in[0];
    const float* gamma      = (const float*)d_in[1];
    const float* w_res      = (const float*)d_in[2];
    const float* w_pre      = (const float*)d_in[3];
    const float* w_post     = (const float*)d_in[4];
    const float* beta_res   = (const float*)d_in[5];
    const float* beta_pre   = (const float*)d_in[6];
    const float* beta_post  = (const float*)d_in[7];
    const float* alpha_res  = (const float*)d_in[8];
    const float* alpha_pre  = (const float*)d_in[9];
    const float* alpha_post = (const float*)d_in[10];
    float* out = (float*)d_out;

    float* wf = (float*)d_ws;                     // needs 24*4096*4 = 384 KB
    (void)ws_size;

    fold_gamma<<<NROWS * 4096 / THREADS, THREADS, 0, stream>>>(
        w_res, w_pre, w_post, gamma, wf);

    const int ntok = in_sizes[0] / 4096;          // B*T = 8192
    const int grid = ntok / TOK_PER_BLK;          // 2048

    hc_fused<<<grid, THREADS, 0, stream>>>(resid, wf, beta_res, beta_pre,
                                           beta_post, alpha_res, alpha_pre,
                                           alpha_post, out);
}

// Round 5
// 294.679 us; speedup vs baseline: 1.1961x; 1.0106x over previous
//
#include <hip/hip_runtime.h>
#include <math.h>

#define TOK_PER_BLK 4
#define THREADS 256
#define NROWS 24
#define PCOL 68        // 64 partials + 4 pad
#define TAU_INV 20.0f  // 1/0.05

// ---------------------------------------------------------------------------
// Prelude: fold (1+gamma) into the 24 weight rows, convert to bf16 (RNE), and
// PERMUTE so that in the main kernel thread tid's two uint4 loads deliver
// exactly the 16 k-elements matching its register-resident x quads:
//   p[m][q] = x[k], k = q*1024 + 4*tid .. +3.
// Row layout (2048 uint32 of bf16 pairs): octet o (4 uint32):
//   o <  256 (t=o):      pairs = x-quads q0(4t..4t+3), q1(1024+4t..)
//   o >= 256 (t=o-256):  pairs = x-quads q2(2048+4t..), q3(3072+4t..)
// R8 evidence: 786 MB/dispatch of fp32 weight re-reads served from L3 (L2
// flushed by the resid+out streams) is ~80 us of the 128 us. bf16 halves it.
// Only w is quantized (x, accum stay fp32): absmax adds ~1e-3 vs the 0.03
// already passing.
// ---------------------------------------------------------------------------
__global__ void fold_gamma(const float* __restrict__ w_res,
                           const float* __restrict__ w_pre,
                           const float* __restrict__ w_post,
                           const float* __restrict__ gamma,
                           unsigned int* __restrict__ wf) {
    const int idx = blockIdx.x * THREADS + threadIdx.x;   // 0 .. 24*2048-1
    const int row = idx >> 11;
    const int j   = idx & 2047;          // uint32 within row
    const int o   = j >> 2;              // octet (uint4) index 0..511
    const int pp  = j & 3;               // pair-within-octet
    const int t   = o & 255;
    const int quad = pp >> 1;            // 0: first x-quad of octet, 1: second
    int base;
    if (o < 256) base = (quad == 0) ? (4 * t)        : (1024 + 4 * t);
    else         base = (quad == 0) ? (2048 + 4 * t) : (3072 + 4 * t);
    const int k0 = base + 2 * (pp & 1);

    const float* src = (row < 16) ? (w_res + ((size_t)row << 12))
                     : (row < 20) ? (w_pre + ((size_t)(row - 16) << 12))
                                  : (w_post + ((size_t)(row - 20) << 12));
    float v0 = src[k0]     * (1.0f + gamma[k0]);
    float v1 = src[k0 + 1] * (1.0f + gamma[k0 + 1]);
    unsigned int u0 = __float_as_uint(v0);
    u0 += 0x7fffu + ((u0 >> 16) & 1u);                    // RNE to bf16
    unsigned int u1 = __float_as_uint(v1);
    u1 += 0x7fffu + ((u1 >> 16) & 1u);
    wf[idx] = (u0 >> 16) | (u1 & 0xffff0000u);
}

// One block = 4 tokens, 256 threads; thread tid holds float4 (q*256+tid) of
// each token in REGISTERS; bf16 weights stream through a CHUNK=1 register
// dbuf (2 uint4 loads/row vs R8's 4 float4).
// ALLOCATOR NOTE (R4/R5/R7/R8): the allocator spills toward 2x the declared
// min-waves/EU. (256,2) -> 128-reg budget -> WRITE_SIZE came back exactly
// 131072 KB (zero spill). Keep (256,2). Tripwire: WRITE_SIZE > 140 MB or
// VGPR_Count <= 84 with excess WRITE means spill returned.
__global__ __launch_bounds__(THREADS, 2)
void hc_fused(const float* __restrict__ resid,
              const unsigned int* __restrict__ wf,
              const float* __restrict__ beta_res,
              const float* __restrict__ beta_pre,
              const float* __restrict__ beta_post,
              const float* __restrict__ p_alpha_res,
              const float* __restrict__ p_alpha_pre,
              const float* __restrict__ p_alpha_post,
              float* __restrict__ out)
{
    __shared__ __align__(16) float sh_part[NROWS * TOK_PER_BLK][PCOL]; // 26.1 KB
    __shared__ __align__(16) float sh_ssqp[TOK_PER_BLK][PCOL];
    __shared__ float sh_raw[TOK_PER_BLK][NROWS];
    __shared__ float sh_ssq[TOK_PER_BLK];
    __shared__ float sh_M[TOK_PER_BLK][16];  // combined remix matrix per token

    const int tid  = threadIdx.x;
    const int wave = tid >> 6;
    const int lane = tid & 63;
    const long tok0 = (long)blockIdx.x * TOK_PER_BLK;

    // ---------------- Phase 1: global -> registers + sumsq ----------------
    const float4* hp = (const float4*)resid + tok0 * 1024;
    float4 p[TOK_PER_BLK][4];
    #pragma unroll
    for (int m = 0; m < TOK_PER_BLK; ++m) {
        #pragma unroll
        for (int q = 0; q < 4; ++q)
            p[m][q] = hp[m * 1024 + q * 256 + tid];
    }
    #pragma unroll
    for (int m = 0; m < TOK_PER_BLK; ++m) {
        float s = 0.f;
        #pragma unroll
        for (int q = 0; q < 4; ++q) {
            float4 v = p[m][q];
            s += v.x * v.x + v.y * v.y + v.z * v.z + v.w * v.w;
        }
        s += __shfl_xor(s, 16, 64);
        s += __shfl_xor(s, 32, 64);
        if (lane < 16) sh_ssqp[m][wave * 16 + lane] = s;
    }

    // ---------------- Phase 2: 24 dots, CHUNK=1 bf16 register dbuf ----------
    const uint4* wp = (const uint4*)wf;      // [24][128] uint4 (512/row? no: 2048 u32 = 512 uint4)

    auto load_row = [&](int e, uint4 (&w)[2]) {
        const uint4* wr = wp + ((size_t)e << 9);   // 512 uint4 per row
        w[0] = wr[tid];
        w[1] = wr[256 + tid];
    };
#define BLO(u) __uint_as_float((u) << 16)
#define BHI(u) __uint_as_float((u) & 0xffff0000u)
    auto comp_row = [&](int e, const uint4 (&W)[2]) {
        const float w00 = BLO(W[0].x), w01 = BHI(W[0].x), w02 = BLO(W[0].y), w03 = BHI(W[0].y);
        const float w10 = BLO(W[0].z), w11 = BHI(W[0].z), w12 = BLO(W[0].w), w13 = BHI(W[0].w);
        const float w20 = BLO(W[1].x), w21 = BHI(W[1].x), w22 = BLO(W[1].y), w23 = BHI(W[1].y);
        const float w30 = BLO(W[1].z), w31 = BHI(W[1].z), w32 = BLO(W[1].w), w33 = BHI(W[1].w);
        #pragma unroll
        for (int m = 0; m < TOK_PER_BLK; ++m) {
            float a = w00 * p[m][0].x + w01 * p[m][0].y + w02 * p[m][0].z + w03 * p[m][0].w
                    + w10 * p[m][1].x + w11 * p[m][1].y + w12 * p[m][1].z + w13 * p[m][1].w
                    + w20 * p[m][2].x + w21 * p[m][2].y + w22 * p[m][2].z + w23 * p[m][2].w
                    + w30 * p[m][3].x + w31 * p[m][3].y + w32 * p[m][3].z + w33 * p[m][3].w;
            a += __shfl_xor(a, 16, 64);
            a += __shfl_xor(a, 32, 64);
            if (lane < 16) sh_part[e * TOK_PER_BLK + m][wave * 16 + lane] = a;
        }
    };

    uint4 wA[2], wB[2];
    load_row(0, wA);
    #pragma unroll 1
    for (int cc = 0; cc < 12; ++cc) {
        load_row(2 * cc + 1, wB);
        comp_row(2 * cc, wA);
        if (cc < 11) load_row(2 * cc + 2, wA);
        comp_row(2 * cc + 1, wB);
    }
#undef BLO
#undef BHI
    __syncthreads();

    // ---------------- Reduce: parallel column sums ----------------
    if (tid < NROWS * TOK_PER_BLK) {           // 96 threads: one (row,token) each
        const int e = tid >> 2, m = tid & 3;
        const float4* src = (const float4*)&sh_part[e * TOK_PER_BLK + m][0];
        float4 s4 = src[0];
        #pragma unroll
        for (int j = 1; j < 16; ++j) {
            float4 v = src[j];
            s4.x += v.x; s4.y += v.y; s4.z += v.z; s4.w += v.w;
        }
        sh_raw[m][e] = s4.x + s4.y + s4.z + s4.w;
    } else if (tid < NROWS * TOK_PER_BLK + TOK_PER_BLK) {
        const int m = tid - NROWS * TOK_PER_BLK;
        const float4* src = (const float4*)&sh_ssqp[m][0];
        float4 s4 = src[0];
        #pragma unroll
        for (int j = 1; j < 16; ++j) {
            float4 v = src[j];
            s4.x += v.x; s4.y += v.y; s4.z += v.z; s4.w += v.w;
        }
        sh_ssq[m] = s4.x + s4.y + s4.z + s4.w;
    }
    __syncthreads();

    // ---------------- Phase 3: sinkhorn + gates (one wave per token) --------
    // Produces the COMBINED matrix M[i][j] = Hres[i][j] + Hpost[i]*Hpre[j],
    // so phase 4 is just out = M . x per d-element.
    {
        const int m   = wave;
        const int idx = lane & 15;     // (i,j): i = idx>>2, j = idx&3
        const int jj  = idx & 3;

        float ss    = sh_ssq[m];
        float scale = 64.0f / fmaxf(sqrtf(ss), 1e-12f);

        const float a_res  = p_alpha_res[0];
        const float a_pre  = p_alpha_pre[0];
        const float a_post = p_alpha_post[0];

        float Z = (beta_res[idx] + a_res * scale * sh_raw[m][idx]) * TAU_INV;
        float u = 0.f, v = 0.f;
        #pragma unroll 1
        for (int it = 0; it < 10; ++it) {
            float t  = Z + v;
            float mx = t;
            mx = fmaxf(mx, __shfl_xor(mx, 1, 64));
            mx = fmaxf(mx, __shfl_xor(mx, 2, 64));
            float sm = __expf(t - mx);
            sm += __shfl_xor(sm, 1, 64);
            sm += __shfl_xor(sm, 2, 64);
            u = -(mx + __logf(sm));
            t  = Z + u;
            mx = t;
            mx = fmaxf(mx, __shfl_xor(mx, 4, 64));
            mx = fmaxf(mx, __shfl_xor(mx, 8, 64));
            sm = __expf(t - mx);
            sm += __shfl_xor(sm, 4, 64);
            sm += __shfl_xor(sm, 8, 64);
            v = -(mx + __logf(sm));
        }
        float P = __expf(Z + u + v);           // Hres[i][j] at lane idx

        float lpre = beta_pre[jj] + a_pre * scale * sh_raw[m][16 + jj];
        float mxp = lpre;
        mxp = fmaxf(mxp, __shfl_xor(mxp, 1, 64));
        mxp = fmaxf(mxp, __shfl_xor(mxp, 2, 64));
        float ep = __expf(lpre - mxp);
        float sp = ep;
        sp += __shfl_xor(sp, 1, 64);
        sp += __shfl_xor(sp, 2, 64);
        float hpre = ep / sp;                  // Hpre[jj]
        float lpost = beta_post[jj] + a_post * scale * sh_raw[m][20 + jj];
        float hpost = 2.0f / (1.0f + __expf(-lpost));  // Hpost[jj]

        // Hpost[i]: lane (idx>>2) computed hpost for jj == i.
        float hpost_i = __shfl(hpost, idx >> 2, 64);
        float Mv = P + hpost_i * hpre;
        if (lane < 16) sh_M[m][idx] = Mv;
    }
    __syncthreads();

    // ---------------- Phase 4: out = M . x, store (FULLY UNROLLED) ----------
    #pragma unroll
    for (int m = 0; m < TOK_PER_BLK; ++m) {
        float Mv[16];
        #pragma unroll
        for (int k = 0; k < 16; ++k) Mv[k] = sh_M[m][k];   // broadcast reads

        float4* op = (float4*)out + (tok0 + m) * 1024;
        #pragma unroll
        for (int i = 0; i < 4; ++i) {
            float4 o;
            o.x = Mv[i*4+0]*p[m][0].x + Mv[i*4+1]*p[m][1].x + Mv[i*4+2]*p[m][2].x + Mv[i*4+3]*p[m][3].x;
            o.y = Mv[i*4+0]*p[m][0].y + Mv[i*4+1]*p[m][1].y + Mv[i*4+2]*p[m][2].y + Mv[i*4+3]*p[m][3].y;
            o.z = Mv[i*4+0]*p[m][0].z + Mv[i*4+1]*p[m][1].z + Mv[i*4+2]*p[m][2].z + Mv[i*4+3]*p[m][3].z;
            o.w = Mv[i*4+0]*p[m][0].w + Mv[i*4+1]*p[m][1].w + Mv[i*4+2]*p[m][2].w + Mv[i*4+3]*p[m][3].w;
            op[i * 256 + tid] = o;
        }
    }
}

extern "C" void kernel_launch(void* const* d_in, const int* in_sizes, int n_in,
                              void* d_out, int out_size, void* d_ws, size_t ws_size,
                              hipStream_t stream) {
    const float* resid      = (const float*)d_in[0];
    const float* gamma      = (const float*)d_in[1];
    const float* w_res      = (const float*)d_in[2];
    const float* w_pre      = (const float*)d_in[3];
    const float* w_post     = (const float*)d_in[4];
    const float* beta_res   = (const float*)d_in[5];
    const float* beta_pre   = (const float*)d_in[6];
    const float* beta_post  = (const float*)d_in[7];
    const float* alpha_res  = (const float*)d_in[8];
    const float* alpha_pre  = (const float*)d_in[9];
    const float* alpha_post = (const float*)d_in[10];
    float* out = (float*)d_out;

    unsigned int* wf = (unsigned int*)d_ws;       // 24*2048*4 = 192 KB
    (void)ws_size;

    fold_gamma<<<NROWS * 2048 / THREADS, THREADS, 0, stream>>>(
        w_res, w_pre, w_post, gamma, wf);

    const int ntok = in_sizes[0] / 4096;          // B*T = 8192
    const int grid = ntok / TOK_PER_BLK;          // 2048

    hc_fused<<<grid, THREADS, 0, stream>>>(resid, wf, beta_res, beta_pre,
                                           beta_post, alpha_res, alpha_pre,
                                           alpha_post, out);
}

// Round 6
// 290.187 us; speedup vs baseline: 1.2147x; 1.0155x over previous
//
#include <hip/hip_runtime.h>
#include <math.h>

#define TOK_PER_BLK 2
#define THREADS 256
#define NROWS 24
#define PCOL 68        // 64 partials + 4 pad
#define TAU_INV 20.0f  // 1/0.05

// ---------------------------------------------------------------------------
// Prelude (unchanged from R9): fold (1+gamma) into the 24 weight rows, convert
// to bf16 (RNE), and PERMUTE so thread tid's two uint4 loads deliver exactly
// the 16 k-elements matching its register-resident x quads
// (k = q*1024 + 4*tid .. +3, q = 0..3). Layout valid for any TOK_PER_BLK
// since the per-thread k-mapping is unchanged.
// ---------------------------------------------------------------------------
__global__ void fold_gamma(const float* __restrict__ w_res,
                           const float* __restrict__ w_pre,
                           const float* __restrict__ w_post,
                           const float* __restrict__ gamma,
                           unsigned int* __restrict__ wf) {
    const int idx = blockIdx.x * THREADS + threadIdx.x;   // 0 .. 24*2048-1
    const int row = idx >> 11;
    const int j   = idx & 2047;          // uint32 within row
    const int o   = j >> 2;              // octet (uint4) index 0..511
    const int pp  = j & 3;               // pair-within-octet
    const int t   = o & 255;
    const int quad = pp >> 1;
    int base;
    if (o < 256) base = (quad == 0) ? (4 * t)        : (1024 + 4 * t);
    else         base = (quad == 0) ? (2048 + 4 * t) : (3072 + 4 * t);
    const int k0 = base + 2 * (pp & 1);

    const float* src = (row < 16) ? (w_res + ((size_t)row << 12))
                     : (row < 20) ? (w_pre + ((size_t)(row - 16) << 12))
                                  : (w_post + ((size_t)(row - 20) << 12));
    float v0 = src[k0]     * (1.0f + gamma[k0]);
    float v1 = src[k0 + 1] * (1.0f + gamma[k0 + 1]);
    unsigned int u0 = __float_as_uint(v0);
    u0 += 0x7fffu + ((u0 >> 16) & 1u);                    // RNE to bf16
    unsigned int u1 = __float_as_uint(v1);
    u1 += 0x7fffu + ((u1 >> 16) & 1u);
    wf[idx] = (u0 >> 16) | (u1 & 0xffff0000u);
}

// R10 STRUCTURE CHANGE: TOK_PER_BLK 4 -> 2, grid 2048 -> 4096.
// R9 diagnosis: 2.3 blocks resident (29% occ) x 85%-stalled waves. Residency
// was LDS-capped at 5 blocks (28 KB) and waves starved by long per-block
// chains. Halving the block: x regs 64->32 (live set ~70), LDS 28->14 KB
// (cap ~7 blocks/CU = 28 waves), per-row FMA chain halves. Weight re-reads
// double to 393 MB but are L2-served (R9: FETCH 66 MB << input, weights never
// hit HBM; L2 time ~6 us, overlapped).
// ALLOCATOR NOTE (R4/R5/R7/R8): allocator spills toward 2x declared
// min-waves/EU; keep (256,2). Tripwire: WRITE_SIZE != 131072 KB means spill.
__global__ __launch_bounds__(THREADS, 2)
void hc_fused(const float* __restrict__ resid,
              const unsigned int* __restrict__ wf,
              const float* __restrict__ beta_res,
              const float* __restrict__ beta_pre,
              const float* __restrict__ beta_post,
              const float* __restrict__ p_alpha_res,
              const float* __restrict__ p_alpha_pre,
              const float* __restrict__ p_alpha_post,
              float* __restrict__ out)
{
    __shared__ __align__(16) float sh_part[NROWS * TOK_PER_BLK][PCOL]; // 13.1 KB
    __shared__ __align__(16) float sh_ssqp[TOK_PER_BLK][PCOL];
    __shared__ float sh_raw[TOK_PER_BLK][NROWS];
    __shared__ float sh_ssq[TOK_PER_BLK];
    __shared__ float sh_M[TOK_PER_BLK][16];  // combined remix matrix per token

    const int tid  = threadIdx.x;
    const int wave = tid >> 6;
    const int lane = tid & 63;
    const long tok0 = (long)blockIdx.x * TOK_PER_BLK;

    // ---------------- Phase 1: global -> registers + sumsq ----------------
    const float4* hp = (const float4*)resid + tok0 * 1024;
    float4 p[TOK_PER_BLK][4];
    #pragma unroll
    for (int m = 0; m < TOK_PER_BLK; ++m) {
        #pragma unroll
        for (int q = 0; q < 4; ++q)
            p[m][q] = hp[m * 1024 + q * 256 + tid];
    }
    #pragma unroll
    for (int m = 0; m < TOK_PER_BLK; ++m) {
        float s = 0.f;
        #pragma unroll
        for (int q = 0; q < 4; ++q) {
            float4 v = p[m][q];
            s += v.x * v.x + v.y * v.y + v.z * v.z + v.w * v.w;
        }
        s += __shfl_xor(s, 16, 64);
        s += __shfl_xor(s, 32, 64);
        if (lane < 16) sh_ssqp[m][wave * 16 + lane] = s;
    }

    // ---------------- Phase 2: 24 dots, CHUNK=1 bf16 register dbuf ----------
    const uint4* wp = (const uint4*)wf;      // 512 uint4 per row

    auto load_row = [&](int e, uint4 (&w)[2]) {
        const uint4* wr = wp + ((size_t)e << 9);
        w[0] = wr[tid];
        w[1] = wr[256 + tid];
    };
#define BLO(u) __uint_as_float((u) << 16)
#define BHI(u) __uint_as_float((u) & 0xffff0000u)
    auto comp_row = [&](int e, const uint4 (&W)[2]) {
        const float w00 = BLO(W[0].x), w01 = BHI(W[0].x), w02 = BLO(W[0].y), w03 = BHI(W[0].y);
        const float w10 = BLO(W[0].z), w11 = BHI(W[0].z), w12 = BLO(W[0].w), w13 = BHI(W[0].w);
        const float w20 = BLO(W[1].x), w21 = BHI(W[1].x), w22 = BLO(W[1].y), w23 = BHI(W[1].y);
        const float w30 = BLO(W[1].z), w31 = BHI(W[1].z), w32 = BLO(W[1].w), w33 = BHI(W[1].w);
        #pragma unroll
        for (int m = 0; m < TOK_PER_BLK; ++m) {
            float a = w00 * p[m][0].x + w01 * p[m][0].y + w02 * p[m][0].z + w03 * p[m][0].w
                    + w10 * p[m][1].x + w11 * p[m][1].y + w12 * p[m][1].z + w13 * p[m][1].w
                    + w20 * p[m][2].x + w21 * p[m][2].y + w22 * p[m][2].z + w23 * p[m][2].w
                    + w30 * p[m][3].x + w31 * p[m][3].y + w32 * p[m][3].z + w33 * p[m][3].w;
            a += __shfl_xor(a, 16, 64);
            a += __shfl_xor(a, 32, 64);
            if (lane < 16) sh_part[e * TOK_PER_BLK + m][wave * 16 + lane] = a;
        }
    };

    uint4 wA[2], wB[2];
    load_row(0, wA);
    #pragma unroll 1
    for (int cc = 0; cc < 12; ++cc) {
        load_row(2 * cc + 1, wB);
        comp_row(2 * cc, wA);
        if (cc < 11) load_row(2 * cc + 2, wA);
        comp_row(2 * cc + 1, wB);
    }
#undef BLO
#undef BHI
    __syncthreads();

    // ---------------- Reduce: parallel column sums ----------------
    if (tid < NROWS * TOK_PER_BLK) {           // 48 threads: one (row,token) each
        const float4* src = (const float4*)&sh_part[tid][0];
        float4 s4 = src[0];
        #pragma unroll
        for (int j = 1; j < 16; ++j) {
            float4 v = src[j];
            s4.x += v.x; s4.y += v.y; s4.z += v.z; s4.w += v.w;
        }
        sh_raw[tid & (TOK_PER_BLK - 1)][tid >> 1] = s4.x + s4.y + s4.z + s4.w;
    } else if (tid < NROWS * TOK_PER_BLK + TOK_PER_BLK) {
        const int m = tid - NROWS * TOK_PER_BLK;
        const float4* src = (const float4*)&sh_ssqp[m][0];
        float4 s4 = src[0];
        #pragma unroll
        for (int j = 1; j < 16; ++j) {
            float4 v = src[j];
            s4.x += v.x; s4.y += v.y; s4.z += v.z; s4.w += v.w;
        }
        sh_ssq[m] = s4.x + s4.y + s4.z + s4.w;
    }
    __syncthreads();

    // ---------------- Phase 3: sinkhorn + gates (wave m -> token m) ---------
    // Produces M[i][j] = Hres[i][j] + Hpost[i]*Hpre[j]; waves 2,3 idle here.
    if (wave < TOK_PER_BLK) {
        const int m   = wave;
        const int idx = lane & 15;     // (i,j): i = idx>>2, j = idx&3
        const int jj  = idx & 3;

        float ss    = sh_ssq[m];
        float scale = 64.0f / fmaxf(sqrtf(ss), 1e-12f);

        const float a_res  = p_alpha_res[0];
        const float a_pre  = p_alpha_pre[0];
        const float a_post = p_alpha_post[0];

        float Z = (beta_res[idx] + a_res * scale * sh_raw[m][idx]) * TAU_INV;
        float u = 0.f, v = 0.f;
        #pragma unroll 1
        for (int it = 0; it < 10; ++it) {
            float t  = Z + v;
            float mx = t;
            mx = fmaxf(mx, __shfl_xor(mx, 1, 64));
            mx = fmaxf(mx, __shfl_xor(mx, 2, 64));
            float sm = __expf(t - mx);
            sm += __shfl_xor(sm, 1, 64);
            sm += __shfl_xor(sm, 2, 64);
            u = -(mx + __logf(sm));
            t  = Z + u;
            mx = t;
            mx = fmaxf(mx, __shfl_xor(mx, 4, 64));
            mx = fmaxf(mx, __shfl_xor(mx, 8, 64));
            sm = __expf(t - mx);
            sm += __shfl_xor(sm, 4, 64);
            sm += __shfl_xor(sm, 8, 64);
            v = -(mx + __logf(sm));
        }
        float P = __expf(Z + u + v);           // Hres[i][j] at lane idx

        float lpre = beta_pre[jj] + a_pre * scale * sh_raw[m][16 + jj];
        float mxp = lpre;
        mxp = fmaxf(mxp, __shfl_xor(mxp, 1, 64));
        mxp = fmaxf(mxp, __shfl_xor(mxp, 2, 64));
        float ep = __expf(lpre - mxp);
        float sp = ep;
        sp += __shfl_xor(sp, 1, 64);
        sp += __shfl_xor(sp, 2, 64);
        float hpre = ep / sp;                  // Hpre[jj]
        float lpost = beta_post[jj] + a_post * scale * sh_raw[m][20 + jj];
        float hpost = 2.0f / (1.0f + __expf(-lpost));  // Hpost[jj]

        // Hpost[i]: lane (idx>>2) computed hpost for jj == i.
        float hpost_i = __shfl(hpost, idx >> 2, 64);
        float Mv = P + hpost_i * hpre;
        if (lane < 16) sh_M[m][idx] = Mv;
    }
    __syncthreads();

    // ---------------- Phase 4: out = M . x, store (FULLY UNROLLED) ----------
    #pragma unroll
    for (int m = 0; m < TOK_PER_BLK; ++m) {
        float Mv[16];
        #pragma unroll
        for (int k = 0; k < 16; ++k) Mv[k] = sh_M[m][k];   // broadcast reads

        float4* op = (float4*)out + (tok0 + m) * 1024;
        #pragma unroll
        for (int i = 0; i < 4; ++i) {
            float4 o;
            o.x = Mv[i*4+0]*p[m][0].x + Mv[i*4+1]*p[m][1].x + Mv[i*4+2]*p[m][2].x + Mv[i*4+3]*p[m][3].x;
            o.y = Mv[i*4+0]*p[m][0].y + Mv[i*4+1]*p[m][1].y + Mv[i*4+2]*p[m][2].y + Mv[i*4+3]*p[m][3].y;
            o.z = Mv[i*4+0]*p[m][0].z + Mv[i*4+1]*p[m][1].z + Mv[i*4+2]*p[m][2].z + Mv[i*4+3]*p[m][3].z;
            o.w = Mv[i*4+0]*p[m][0].w + Mv[i*4+1]*p[m][1].w + Mv[i*4+2]*p[m][2].w + Mv[i*4+3]*p[m][3].w;
            op[i * 256 + tid] = o;
        }
    }
}

extern "C" void kernel_launch(void* const* d_in, const int* in_sizes, int n_in,
                              void* d_out, int out_size, void* d_ws, size_t ws_size,
                              hipStream_t stream) {
    const float* resid      = (const float*)d_in[0];
    const float* gamma      = (const float*)d_in[1];
    const float* w_res      = (const float*)d_in[2];
    const float* w_pre      = (const float*)d_in[3];
    const float* w_post     = (const float*)d_in[4];
    const float* beta_res   = (const float*)d_in[5];
    const float* beta_pre   = (const float*)d_in[6];
    const float* beta_post  = (const float*)d_in[7];
    const float* alpha_res  = (const float*)d_in[8];
    const float* alpha_pre  = (const float*)d_in[9];
    const float* alpha_post = (const float*)d_in[10];
    float* out = (float*)d_out;

    unsigned int* wf = (unsigned int*)d_ws;       // 24*2048*4 = 192 KB
    (void)ws_size;

    fold_gamma<<<NROWS * 2048 / THREADS, THREADS, 0, stream>>>(
        w_res, w_pre, w_post, gamma, wf);

    const int ntok = in_sizes[0] / 4096;          // B*T = 8192
    const int grid = ntok / TOK_PER_BLK;          // 4096

    hc_fused<<<grid, THREADS, 0, stream>>>(resid, wf, beta_res, beta_pre,
                                           beta_post, alpha_res, alpha_pre,
                                           alpha_post, out);
}

// Round 7
// 283.076 us; speedup vs baseline: 1.2452x; 1.0251x over previous
//
#include <hip/hip_runtime.h>
#include <math.h>

#define TOK_PER_BLK 2
#define THREADS 256
#define NROWS 24
#define PCOL 68        // 64 partials + 4 pad
#define TAU_INV 20.0f  // 1/0.05

typedef _Float16 half2_t __attribute__((ext_vector_type(2)));

// ---------------------------------------------------------------------------
// Prelude: fold (1+gamma) into the 24 weight rows, convert to f16 PAIRS
// (low half = even k), PERMUTED so thread tid's two uint4 loads deliver the
// 16 k-elements matching its x quads (k = q*1024 + 4*tid .. +3, q=0..3).
// f16 (10-bit mantissa) is MORE precise than the bf16 that passed R9/R10.
// ---------------------------------------------------------------------------
__global__ void fold_gamma(const float* __restrict__ w_res,
                           const float* __restrict__ w_pre,
                           const float* __restrict__ w_post,
                           const float* __restrict__ gamma,
                           unsigned int* __restrict__ wf) {
    const int idx = blockIdx.x * THREADS + threadIdx.x;   // 0 .. 24*2048-1
    const int row = idx >> 11;
    const int j   = idx & 2047;          // uint32 within row
    const int o   = j >> 2;              // octet (uint4) index 0..511
    const int pp  = j & 3;               // pair-within-octet
    const int t   = o & 255;
    const int quad = pp >> 1;
    int base;
    if (o < 256) base = (quad == 0) ? (4 * t)        : (1024 + 4 * t);
    else         base = (quad == 0) ? (2048 + 4 * t) : (3072 + 4 * t);
    const int k0 = base + 2 * (pp & 1);

    const float* src = (row < 16) ? (w_res + ((size_t)row << 12))
                     : (row < 20) ? (w_pre + ((size_t)(row - 16) << 12))
                                  : (w_post + ((size_t)(row - 20) << 12));
    float v0 = src[k0]     * (1.0f + gamma[k0]);
    float v1 = src[k0 + 1] * (1.0f + gamma[k0 + 1]);
    union { _Float16 h[2]; unsigned int u; } cvt;
    cvt.h[0] = (_Float16)v0;             // low half  = even k (fdot2 .x)
    cvt.h[1] = (_Float16)v1;             // high half = odd k  (fdot2 .y)
    wf[idx] = cvt.u;
}

// R11: v_dot2_f32_f16 phase 2. R10 falsified the residency theory (occ 29->48,
// dur 120 flat). Counters: VALUBusy 42% x 120us = 50us ISSUE FLOOR, dominated
// by phase 2's 16 bf16-unpacks + 32 FMA per row. fdot2 compresses that to
// 16 dots, no unpacks (~24 VALU/row vs ~58). x kept ONLY as packed f16 after
// the fp32 sumsq (phase-4 unpack error ~2e-3 << passing 0.0625): live set
// ~90 regs. Weight prefetch depth 2 (triple buffer) to cover L2 latency.
// ALLOCATOR NOTE (R4/R5/R7/R8): allocator spills toward 2x declared
// min-waves/EU; keep (256,2). Tripwire: WRITE_SIZE != 131072 KB means spill.
__global__ __launch_bounds__(THREADS, 2)
void hc_fused(const float* __restrict__ resid,
              const unsigned int* __restrict__ wf,
              const float* __restrict__ beta_res,
              const float* __restrict__ beta_pre,
              const float* __restrict__ beta_post,
              const float* __restrict__ p_alpha_res,
              const float* __restrict__ p_alpha_pre,
              const float* __restrict__ p_alpha_post,
              float* __restrict__ out)
{
    __shared__ __align__(16) float sh_part[NROWS * TOK_PER_BLK][PCOL]; // 13.1 KB
    __shared__ __align__(16) float sh_ssqp[TOK_PER_BLK][PCOL];
    __shared__ float sh_raw[TOK_PER_BLK][NROWS];
    __shared__ float sh_ssq[TOK_PER_BLK];
    __shared__ float sh_M[TOK_PER_BLK][16];  // combined remix matrix per token

    const int tid  = threadIdx.x;
    const int wave = tid >> 6;
    const int lane = tid & 63;
    const long tok0 = (long)blockIdx.x * TOK_PER_BLK;

    // ---------- Phase 1: global -> fp32 sumsq -> packed f16 registers -------
    const float4* hp = (const float4*)resid + tok0 * 1024;
    half2_t xh[TOK_PER_BLK][8];    // xh[m][2q]=(c0,c1), xh[m][2q+1]=(c2,c3)
    #pragma unroll
    for (int m = 0; m < TOK_PER_BLK; ++m) {
        float4 pf[4];
        #pragma unroll
        for (int q = 0; q < 4; ++q)
            pf[q] = hp[m * 1024 + q * 256 + tid];
        float s = 0.f;
        #pragma unroll
        for (int q = 0; q < 4; ++q) {
            float4 v = pf[q];
            s += v.x * v.x + v.y * v.y + v.z * v.z + v.w * v.w;
            xh[m][2 * q]     = half2_t{(_Float16)v.x, (_Float16)v.y};
            xh[m][2 * q + 1] = half2_t{(_Float16)v.z, (_Float16)v.w};
        }
        s += __shfl_xor(s, 16, 64);
        s += __shfl_xor(s, 32, 64);
        if (lane < 16) sh_ssqp[m][wave * 16 + lane] = s;
    }

    // ---------- Phase 2: 24 dots via fdot2, depth-2 (triple) prefetch -------
    const uint4* wp = (const uint4*)wf;      // 512 uint4 per row

    auto load_row = [&](int e, uint4 (&w)[2]) {
        const uint4* wr = wp + ((size_t)e << 9);
        w[0] = wr[tid];
        w[1] = wr[256 + tid];
    };
#define H2(u) __builtin_bit_cast(half2_t, (u))
    auto comp_row = [&](int e, const uint4 (&W)[2]) {
        #pragma unroll
        for (int m = 0; m < TOK_PER_BLK; ++m) {
            float a = 0.f;
            a = __builtin_amdgcn_fdot2(H2(W[0].x), xh[m][0], a, false);
            a = __builtin_amdgcn_fdot2(H2(W[0].y), xh[m][1], a, false);
            a = __builtin_amdgcn_fdot2(H2(W[0].z), xh[m][2], a, false);
            a = __builtin_amdgcn_fdot2(H2(W[0].w), xh[m][3], a, false);
            a = __builtin_amdgcn_fdot2(H2(W[1].x), xh[m][4], a, false);
            a = __builtin_amdgcn_fdot2(H2(W[1].y), xh[m][5], a, false);
            a = __builtin_amdgcn_fdot2(H2(W[1].z), xh[m][6], a, false);
            a = __builtin_amdgcn_fdot2(H2(W[1].w), xh[m][7], a, false);
            a += __shfl_xor(a, 16, 64);
            a += __shfl_xor(a, 32, 64);
            if (lane < 16) sh_part[e * TOK_PER_BLK + m][wave * 16 + lane] = a;
        }
    };
#undef H2

    uint4 wA[2], wB[2], wC[2];
    load_row(0, wA);
    load_row(1, wB);
    #pragma unroll 1
    for (int c = 0; c < 8; ++c) {            // 3 rows per iter: 3c, 3c+1, 3c+2
        load_row(3 * c + 2, wC);
        comp_row(3 * c, wA);
        if (3 * c + 3 < NROWS) load_row(3 * c + 3, wA);
        comp_row(3 * c + 1, wB);
        if (3 * c + 4 < NROWS) load_row(3 * c + 4, wB);
        comp_row(3 * c + 2, wC);
    }
    __syncthreads();

    // ---------------- Reduce: parallel column sums ----------------
    if (tid < NROWS * TOK_PER_BLK) {           // 48 threads: one (row,token) each
        const float4* src = (const float4*)&sh_part[tid][0];
        float4 s4 = src[0];
        #pragma unroll
        for (int j = 1; j < 16; ++j) {
            float4 v = src[j];
            s4.x += v.x; s4.y += v.y; s4.z += v.z; s4.w += v.w;
        }
        sh_raw[tid & (TOK_PER_BLK - 1)][tid >> 1] = s4.x + s4.y + s4.z + s4.w;
    } else if (tid < NROWS * TOK_PER_BLK + TOK_PER_BLK) {
        const int m = tid - NROWS * TOK_PER_BLK;
        const float4* src = (const float4*)&sh_ssqp[m][0];
        float4 s4 = src[0];
        #pragma unroll
        for (int j = 1; j < 16; ++j) {
            float4 v = src[j];
            s4.x += v.x; s4.y += v.y; s4.z += v.z; s4.w += v.w;
        }
        sh_ssq[m] = s4.x + s4.y + s4.z + s4.w;
    }
    __syncthreads();

    // ---------------- Phase 3: sinkhorn + gates (wave m -> token m) ---------
    if (wave < TOK_PER_BLK) {
        const int m   = wave;
        const int idx = lane & 15;     // (i,j): i = idx>>2, j = idx&3
        const int jj  = idx & 3;

        float ss    = sh_ssq[m];
        float scale = 64.0f / fmaxf(sqrtf(ss), 1e-12f);

        const float a_res  = p_alpha_res[0];
        const float a_pre  = p_alpha_pre[0];
        const float a_post = p_alpha_post[0];

        float Z = (beta_res[idx] + a_res * scale * sh_raw[m][idx]) * TAU_INV;
        float u = 0.f, v = 0.f;
        #pragma unroll 1
        for (int it = 0; it < 10; ++it) {
            float t  = Z + v;
            float mx = t;
            mx = fmaxf(mx, __shfl_xor(mx, 1, 64));
            mx = fmaxf(mx, __shfl_xor(mx, 2, 64));
            float sm = __expf(t - mx);
            sm += __shfl_xor(sm, 1, 64);
            sm += __shfl_xor(sm, 2, 64);
            u = -(mx + __logf(sm));
            t  = Z + u;
            mx = t;
            mx = fmaxf(mx, __shfl_xor(mx, 4, 64));
            mx = fmaxf(mx, __shfl_xor(mx, 8, 64));
            sm = __expf(t - mx);
            sm += __shfl_xor(sm, 4, 64);
            sm += __shfl_xor(sm, 8, 64);
            v = -(mx + __logf(sm));
        }
        float P = __expf(Z + u + v);           // Hres[i][j] at lane idx

        float lpre = beta_pre[jj] + a_pre * scale * sh_raw[m][16 + jj];
        float mxp = lpre;
        mxp = fmaxf(mxp, __shfl_xor(mxp, 1, 64));
        mxp = fmaxf(mxp, __shfl_xor(mxp, 2, 64));
        float ep = __expf(lpre - mxp);
        float sp = ep;
        sp += __shfl_xor(sp, 1, 64);
        sp += __shfl_xor(sp, 2, 64);
        float hpre = ep / sp;                  // Hpre[jj]
        float lpost = beta_post[jj] + a_post * scale * sh_raw[m][20 + jj];
        float hpost = 2.0f / (1.0f + __expf(-lpost));  // Hpost[jj]

        float hpost_i = __shfl(hpost, idx >> 2, 64);   // Hpost[i]
        float Mv = P + hpost_i * hpre;                 // M = Hres + Hpost x Hpre
        if (lane < 16) sh_M[m][idx] = Mv;
    }
    __syncthreads();

    // ---------------- Phase 4: out = M . x (x unpacked from f16) ------------
    #pragma unroll
    for (int m = 0; m < TOK_PER_BLK; ++m) {
        float Mv[16];
        #pragma unroll
        for (int k = 0; k < 16; ++k) Mv[k] = sh_M[m][k];   // broadcast reads

        float xm[16];   // xm[4q+c] = stream q, component c (fully unrolled)
        #pragma unroll
        for (int q = 0; q < 4; ++q) {
            xm[4*q + 0] = (float)xh[m][2*q][0];
            xm[4*q + 1] = (float)xh[m][2*q][1];
            xm[4*q + 2] = (float)xh[m][2*q + 1][0];
            xm[4*q + 3] = (float)xh[m][2*q + 1][1];
        }

        float4* op = (float4*)out + (tok0 + m) * 1024;
        #pragma unroll
        for (int i = 0; i < 4; ++i) {
            float4 o;
            o.x = Mv[i*4+0]*xm[0] + Mv[i*4+1]*xm[4]  + Mv[i*4+2]*xm[8]  + Mv[i*4+3]*xm[12];
            o.y = Mv[i*4+0]*xm[1] + Mv[i*4+1]*xm[5]  + Mv[i*4+2]*xm[9]  + Mv[i*4+3]*xm[13];
            o.z = Mv[i*4+0]*xm[2] + Mv[i*4+1]*xm[6]  + Mv[i*4+2]*xm[10] + Mv[i*4+3]*xm[14];
            o.w = Mv[i*4+0]*xm[3] + Mv[i*4+1]*xm[7]  + Mv[i*4+2]*xm[11] + Mv[i*4+3]*xm[15];
            op[i * 256 + tid] = o;
        }
    }
}

extern "C" void kernel_launch(void* const* d_in, const int* in_sizes, int n_in,
                              void* d_out, int out_size, void* d_ws, size_t ws_size,
                              hipStream_t stream) {
    const float* resid      = (const float*)d_in[0];
    const float* gamma      = (const float*)d_in[1];
    const float* w_res      = (const float*)d_in[2];
    const float* w_pre      = (const float*)d_in[3];
    const float* w_post     = (const float*)d_in[4];
    const float* beta_res   = (const float*)d_in[5];
    const float* beta_pre   = (const float*)d_in[6];
    const float* beta_post  = (const float*)d_in[7];
    const float* alpha_res  = (const float*)d_in[8];
    const float* alpha_pre  = (const float*)d_in[9];
    const float* alpha_post = (const float*)d_in[10];
    float* out = (float*)d_out;

    unsigned int* wf = (unsigned int*)d_ws;       // 24*2048*4 = 192 KB
    (void)ws_size;

    fold_gamma<<<NROWS * 2048 / THREADS, THREADS, 0, stream>>>(
        w_res, w_pre, w_post, gamma, wf);

    const int ntok = in_sizes[0] / 4096;          // B*T = 8192
    const int grid = ntok / TOK_PER_BLK;          // 4096

    hc_fused<<<grid, THREADS, 0, stream>>>(resid, wf, beta_res, beta_pre,
                                           beta_post, alpha_res, alpha_pre,
                                           alpha_post, out);
}